// Round 3
// baseline (62961.017 us; speedup 1.0000x reference)
//
#include <hip/hip_runtime.h>

typedef unsigned short u16;
typedef unsigned int   u32;
typedef short v8s __attribute__((ext_vector_type(8)));
typedef float v4f __attribute__((ext_vector_type(4)));

#define NBLK 256
#define SCALE_F 0.08838834764831845f  // 1/sqrt(128)

// ---------- ws layout (float offsets) ----------
#define O_QUERY  0           // 512
#define O_NQ     512         // 512
#define O_WK     1024        // 2048
#define O_KB     3072        // 4
#define O_FLAG   3080        // ints: flag, nan counter
#define O_BARS   3088        // ints: barrier cnt, gen (16)
#define O_AV     4096        // 131072
#define O_HEAD   135168      // 32768
#define O_CTXT   167936      // 32768
#define O_EMBG   200704      // 4096*34 fp32, REORDERED row index
#define O_CTXG   339968      // 4096*64 fp32, REORDERED
#define O_CTXP1  602112      // 512*64 fp32, natural
#define O_B1R    634880      // 4096 fp32 reordered bias L1
#define O_B2R    638976      // 2048 fp32 reordered bias L2
#define O_LABT   641024      // 255*64 ints (pad 16384)
#define O_H0B    657408      // 2 bufs x 64x1024 bf16 = 65536 f
#define O_H1B    722944      // 65536 f
#define O_H2B    788480      // 2 bufs x 64x512 bf16 = 32768 f
#define O_YT     821248      // 64x512 bf16 = 16384 f
#define O_AL0    837632      // 256*32*64*8 bf16 = 2097152 f
#define O_AL1    2934784     // 256*64*64*8 bf16 = 4194304 f
#define O_AL2    7129088     // 128*48*64*8 bf16 = 1572864 f
#define O_AP1    8701952     // 32*16*64*8 bf16 = 131072 f
#define O_AP2    8833024     // 3*16*64*8 bf16 = 12288 f
#define O_CANON  8845312     // canonical bf16 (~6.08M u16) -> total ~47.5 MB

__device__ __forceinline__ float bfc(u16 x) { return __uint_as_float(((u32)x) << 16); }
__device__ __forceinline__ float2 bfpair(u32 u) {
    return make_float2(__uint_as_float(u << 16), __uint_as_float(u & 0xffff0000u));
}
__device__ __forceinline__ u16 f2bf(float f) {
    u32 u = __float_as_uint(f);
    u += 0x7fffu + ((u >> 16) & 1u);
    return (u16)(u >> 16);
}
__device__ __forceinline__ float sigf(float x) { return 1.0f / (1.0f + __expf(-x)); }
__device__ __forceinline__ float tanh_(float x) { return 2.0f / (1.0f + __expf(-2.0f * x)) - 1.0f; }

union U4 { uint4 u; v8s s; };

__device__ __forceinline__ void fma8(float& acc, uint4 a, const float h[8]) {
    float2 p;
    p = bfpair(a.x); acc = fmaf(h[0], p.x, acc); acc = fmaf(h[1], p.y, acc);
    p = bfpair(a.y); acc = fmaf(h[2], p.x, acc); acc = fmaf(h[3], p.y, acc);
    p = bfpair(a.z); acc = fmaf(h[4], p.x, acc); acc = fmaf(h[5], p.y, acc);
    p = bfpair(a.w); acc = fmaf(h[6], p.x, acc); acc = fmaf(h[7], p.y, acc);
}

// reordered row index for LSTM gate row r (natural) with H h-rows per gate
__device__ __forceinline__ int reord(int row, int hbits) {
    int hmask = (1 << hbits) - 1;
    int g = row >> hbits, hr = row & hmask;
    return (hr >> 2) * 16 + (hr & 3) * 4 + g;
}

// ---------------- dtype detect + canonicalize ----------------

__global__ __launch_bounds__(256) void las_detect(const u16* w, int* flag) {
    __shared__ int s[256];
    int bad = 0;
    for (int i = threadIdx.x; i < 65536; i += 256) {
        u16 v = w[i];
        if ((v & 0x7F80u) == 0x7F80u) bad++;
        else if (fabsf(bfc(v)) > 1e4f) bad++;
    }
    s[threadIdx.x] = bad; __syncthreads();
    for (int o = 128; o; o >>= 1) {
        if (threadIdx.x < o) s[threadIdx.x] += s[threadIdx.x + o];
        __syncthreads();
    }
    if (threadIdx.x == 0) { flag[0] = (s[0] == 0) ? 1 : 0; flag[1] = 0; }
}

#define NSEG 32
struct Cvt {
    const void* src[NSEG];
    unsigned ofs[NSEG + 1];
    unsigned len[NSEG];
};

__global__ __launch_bounds__(256) void las_convert(Cvt c, const int* flag, u16* dst) {
    int isb = flag[0];
    unsigned total = c.ofs[NSEG] >> 1;
    for (unsigned p = blockIdx.x * 256 + threadIdx.x; p < total; p += gridDim.x * 256) {
        unsigned e = p << 1;
        int lo = 0, hi = NSEG;
        while (hi - lo > 1) { int mid = (lo + hi) >> 1; if (c.ofs[mid] <= e) lo = mid; else hi = mid; }
        unsigned local = e - c.ofs[lo];
        u32 out;
        if (local >= c.len[lo]) out = 0;
        else if (isb) out = ((const u32*)c.src[lo])[local >> 1];
        else {
            const float* s = (const float*)c.src[lo];
            out = (u32)f2bf(s[local]) | ((u32)f2bf(s[local + 1]) << 16);
        }
        ((u32*)dst)[p] = out;
    }
}

// load 8 bf16 from a raw input tensor of either dtype (ofs multiple of 8)
__device__ __forceinline__ uint4 ld8(const void* src, size_t ofs, int isb) {
    if (isb) return *(const uint4*)((const u16*)src + ofs);
    const float4* fp = (const float4*)((const float*)src + ofs);
    float4 a = fp[0], b = fp[1];
    uint4 r;
    r.x = (u32)f2bf(a.x) | ((u32)f2bf(a.y) << 16);
    r.y = (u32)f2bf(a.z) | ((u32)f2bf(a.w) << 16);
    r.z = (u32)f2bf(b.x) | ((u32)f2bf(b.y) << 16);
    r.w = (u32)f2bf(b.z) | ((u32)f2bf(b.w) << 16);
    return r;
}

// ---------------- one-time kernels ----------------

__global__ __launch_bounds__(256) void las_initA(const u16* h00c, const u16* h01c, const u16* h02c,
                                                 const int* label, u16* h0b1, u16* h1b1, u16* h2b1,
                                                 int* labT, int* bars) {
    int idx = blockIdx.x * 256 + threadIdx.x;   // 65536
    int j = idx & 1023;
    h0b1[idx] = h00c[j];                        // [batch][1024] broadcast
    h1b1[idx] = h01c[j];
    if (idx < 64 * 512) h2b1[idx] = h02c[idx & 511];
    if (idx < 255 * 64) { int t = idx >> 6, b = idx & 63; labT[idx] = label[b * 256 + t]; }
    if (idx < 16) bars[idx] = 0;
}

__global__ __launch_bounds__(256) void las_query(const u16* h02, const u16* W_query,
                                                 const u16* b_query, float* query) {
    int i = blockIdx.x * 256 + threadIdx.x;
    float acc = bfc(b_query[i]);
    const u32* wr = (const u32*)(W_query + (size_t)i * 512);
    const u32* hp = (const u32*)h02;
    for (int h = 0; h < 512; h += 8) {
        uint4 wv = *(const uint4*)(wr + (h >> 1));
        uint4 hv = *(const uint4*)(hp + (h >> 1));
        float2 a, c;
        a = bfpair(wv.x); c = bfpair(hv.x); acc = fmaf(a.x, c.x, acc); acc = fmaf(a.y, c.y, acc);
        a = bfpair(wv.y); c = bfpair(hv.y); acc = fmaf(a.x, c.x, acc); acc = fmaf(a.y, c.y, acc);
        a = bfpair(wv.z); c = bfpair(hv.z); acc = fmaf(a.x, c.x, acc); acc = fmaf(a.y, c.y, acc);
        a = bfpair(wv.w); c = bfpair(hv.w); acc = fmaf(a.x, c.x, acc); acc = fmaf(a.y, c.y, acc);
    }
    query[i] = acc;
}

__global__ __launch_bounds__(256) void las_nq(const float* query, const u16* Wq,
                                              const u16* bq, float* nq) {
    int nd = blockIdx.x * 256 + threadIdx.x;
    float acc = bfc(bq[nd]);
    const u32* wr = (const u32*)(Wq + (size_t)nd * 512);
    for (int h = 0; h < 512; h += 8) {
        uint4 wv = *(const uint4*)(wr + (h >> 1));
        float2 p;
        p = bfpair(wv.x); acc = fmaf(p.x, query[h + 0], acc); acc = fmaf(p.y, query[h + 1], acc);
        p = bfpair(wv.y); acc = fmaf(p.x, query[h + 2], acc); acc = fmaf(p.y, query[h + 3], acc);
        p = bfpair(wv.z); acc = fmaf(p.x, query[h + 4], acc); acc = fmaf(p.y, query[h + 5], acc);
        p = bfpair(wv.w); acc = fmaf(p.x, query[h + 6], acc); acc = fmaf(p.y, query[h + 7], acc);
    }
    nq[nd] = acc;
}

__global__ __launch_bounds__(256) void las_wk(const float* nq, const u16* Wk, const u16* bk,
                                              float* wk, float* kb) {
    int idx = blockIdx.x * 256 + threadIdx.x;
    int n = idx >> 9, h = idx & 511;
    float acc = 0.0f;
    for (int d = 0; d < 128; d++)
        acc = fmaf(nq[n * 128 + d], bfc(Wk[((size_t)(n * 128 + d)) * 512 + h]), acc);
    wk[idx] = acc;
    if (idx < 4) {
        float kk = 0.0f;
        for (int d = 0; d < 128; d++) kk = fmaf(nq[idx * 128 + d], bfc(bk[idx * 128 + d]), kk);
        kb[idx] = kk;
    }
}

__global__ __launch_bounds__(256) void las_attn(const void* keysv, const void* valuesv,
                                                const int* input_len, const int* flag,
                                                const float* wk, const float* kb, float* av) {
    __shared__ float wk_s[2048];
    __shared__ float kb_s[4];
    __shared__ float sm[4][1024];
    __shared__ float red[256];
    __shared__ float stat[4];
    const u16* keysB = (const u16*)keysv;
    const float* keysF = (const float*)keysv;
    const u16* valB = (const u16*)valuesv;
    const float* valF = (const float*)valuesv;
    int b = blockIdx.x, tid = threadIdx.x, isb = flag[0];
    for (int i = tid; i < 2048; i += 256) wk_s[i] = wk[i];
    if (tid < 4) kb_s[tid] = kb[tid];
    __syncthreads();
    int len = input_len[b];
    {
        float acc[4][4];
#pragma unroll
        for (int tl = 0; tl < 4; tl++)
#pragma unroll
            for (int n = 0; n < 4; n++) acc[tl][n] = kb_s[n];
        for (int h = 0; h < 512; h += 8) {
            float kf[4][8];
#pragma unroll
            for (int tl = 0; tl < 4; tl++) {
                int t = tid + 256 * tl;
                size_t base = ((size_t)t * 64 + b) * 512 + h;
                if (isb) {
                    uint4 kv = *(const uint4*)(keysB + base);
                    float2 p;
                    p = bfpair(kv.x); kf[tl][0] = p.x; kf[tl][1] = p.y;
                    p = bfpair(kv.y); kf[tl][2] = p.x; kf[tl][3] = p.y;
                    p = bfpair(kv.z); kf[tl][4] = p.x; kf[tl][5] = p.y;
                    p = bfpair(kv.w); kf[tl][6] = p.x; kf[tl][7] = p.y;
                } else {
                    const float4* kp = (const float4*)(keysF + base);
                    float4 q0 = kp[0], q1 = kp[1];
                    kf[tl][0] = q0.x; kf[tl][1] = q0.y; kf[tl][2] = q0.z; kf[tl][3] = q0.w;
                    kf[tl][4] = q1.x; kf[tl][5] = q1.y; kf[tl][6] = q1.z; kf[tl][7] = q1.w;
                }
            }
#pragma unroll
            for (int i = 0; i < 8; i++) {
                float w0 = wk_s[h + i], w1 = wk_s[512 + h + i];
                float w2 = wk_s[1024 + h + i], w3 = wk_s[1536 + h + i];
#pragma unroll
                for (int tl = 0; tl < 4; tl++) {
                    acc[tl][0] = fmaf(kf[tl][i], w0, acc[tl][0]);
                    acc[tl][1] = fmaf(kf[tl][i], w1, acc[tl][1]);
                    acc[tl][2] = fmaf(kf[tl][i], w2, acc[tl][2]);
                    acc[tl][3] = fmaf(kf[tl][i], w3, acc[tl][3]);
                }
            }
        }
#pragma unroll
        for (int tl = 0; tl < 4; tl++) {
            int t = tid + 256 * tl;
#pragma unroll
            for (int n = 0; n < 4; n++)
                sm[n][t] = (t < len) ? acc[tl][n] * SCALE_F : -1e30f;
        }
    }
    __syncthreads();
    for (int n = 0; n < 4; n++) {
        float m = -1e30f;
        for (int tl = 0; tl < 4; tl++) m = fmaxf(m, sm[n][tid + 256 * tl]);
        red[tid] = m; __syncthreads();
        for (int off = 128; off; off >>= 1) {
            if (tid < off) red[tid] = fmaxf(red[tid], red[tid + off]);
            __syncthreads();
        }
        m = red[0]; __syncthreads();
        float e = 0.0f;
        for (int tl = 0; tl < 4; tl++) {
            int t = tid + 256 * tl;
            float x = (t < len) ? __expf(sm[n][t] - m) : 0.0f;
            sm[n][t] = x; e += x;
        }
        red[tid] = e; __syncthreads();
        for (int off = 128; off; off >>= 1) {
            if (tid < off) red[tid] += red[tid + off];
            __syncthreads();
        }
        if (tid == 0) stat[n] = 1.0f / red[0];
        __syncthreads();
    }
    {
        float a[4][2] = {};
        int h0 = 2 * tid;
        for (int t = 0; t < len; t++) {
            size_t base = ((size_t)t * 64 + b) * 512 + h0;
            float2 p;
            if (isb) p = bfpair(*(const u32*)(valB + base));
            else     p = *(const float2*)(valF + base);
            float s0 = sm[0][t], s1 = sm[1][t], s2 = sm[2][t], s3 = sm[3][t];
            a[0][0] = fmaf(s0, p.x, a[0][0]); a[0][1] = fmaf(s0, p.y, a[0][1]);
            a[1][0] = fmaf(s1, p.x, a[1][0]); a[1][1] = fmaf(s1, p.y, a[1][1]);
            a[2][0] = fmaf(s2, p.x, a[2][0]); a[2][1] = fmaf(s2, p.y, a[2][1]);
            a[3][0] = fmaf(s3, p.x, a[3][0]); a[3][1] = fmaf(s3, p.y, a[3][1]);
        }
#pragma unroll
        for (int n = 0; n < 4; n++) {
            av[((size_t)b * 4 + n) * 512 + h0]     = a[n][0] * stat[n];
            av[((size_t)b * 4 + n) * 512 + h0 + 1] = a[n][1] * stat[n];
        }
    }
}

__global__ __launch_bounds__(256) void las_head(const float* av, const u16* Wv, const u16* bv,
                                                float* head) {
    int idx = blockIdx.x * 256 + threadIdx.x;
    int b = idx >> 9, nd = idx & 511, n = nd >> 7;
    float acc = bfc(bv[nd]);
    const u32* wr = (const u32*)(Wv + (size_t)nd * 512);
    const float* ap = av + ((size_t)b * 4 + n) * 512;
    for (int h = 0; h < 512; h += 8) {
        uint4 wv = *(const uint4*)(wr + (h >> 1));
        float hv[8];
#pragma unroll
        for (int k = 0; k < 8; k++) hv[k] = ap[h + k];
        fma8(acc, wv, hv);
    }
    head[idx] = acc;
}

__global__ __launch_bounds__(256) void las_ctx(const float* head, const u16* W_mh, const u16* b_mh,
                                               float* ctxT) {
    int idx = blockIdx.x * 256 + threadIdx.x;
    int b = idx >> 9, i = idx & 511;
    float acc = bfc(b_mh[i]);
    const u32* wr = (const u32*)(W_mh + (size_t)i * 512);
    const float* hp = head + (size_t)b * 512;
    for (int h = 0; h < 512; h += 8) {
        uint4 wv = *(const uint4*)(wr + (h >> 1));
        float hv[8];
#pragma unroll
        for (int k = 0; k < 8; k++) hv[k] = hp[h + k];
        fma8(acc, wv, hv);
    }
    ctxT[(size_t)i * 64 + b] = acc;
}

// embg REORDERED: embg[reord(row)*34 + v] = dot(Wih0[row][0:512], W_emb[v])
__global__ __launch_bounds__(256) void las_embg(const u16* W_emb, const u16* Wih0, float* embg) {
    int idx = blockIdx.x * 256 + threadIdx.x;
    if (idx >= 4096 * 34) return;
    int row = idx / 34, v = idx - row * 34;
    const u32* wr = (const u32*)(Wih0 + (size_t)row * 1024);
    const u32* er = (const u32*)(W_emb + (size_t)v * 512);
    float acc = 0.0f;
    for (int h = 0; h < 512; h += 8) {
        uint4 wv = *(const uint4*)(wr + (h >> 1));
        uint4 ev = *(const uint4*)(er + (h >> 1));
        float2 a, c;
        a = bfpair(wv.x); c = bfpair(ev.x); acc = fmaf(a.x, c.x, acc); acc = fmaf(a.y, c.y, acc);
        a = bfpair(wv.y); c = bfpair(ev.y); acc = fmaf(a.x, c.x, acc); acc = fmaf(a.y, c.y, acc);
        a = bfpair(wv.z); c = bfpair(ev.z); acc = fmaf(a.x, c.x, acc); acc = fmaf(a.y, c.y, acc);
        a = bfpair(wv.w); c = bfpair(ev.w); acc = fmaf(a.x, c.x, acc); acc = fmaf(a.y, c.y, acc);
    }
    embg[(size_t)reord(row, 10) * 34 + v] = acc;
}

// ctxg REORDERED (includes bih0+bhh0)
__global__ __launch_bounds__(256) void las_ctxg(const float* ctxT, const u16* Wih0,
                                                const u16* bih0, const u16* bhh0, float* ctxg) {
    int lane = threadIdx.x & 63, w = threadIdx.x >> 6;
    int row = blockIdx.x * 4 + w;
    float acc = bfc(bih0[row]) + bfc(bhh0[row]);
    const u32* wr = (const u32*)(Wih0 + (size_t)row * 1024 + 512);
    for (int h = 0; h < 512; h += 8) {
        float hv[8];
#pragma unroll
        for (int i = 0; i < 8; i++) hv[i] = ctxT[(size_t)(h + i) * 64 + lane];
        uint4 wv = *(const uint4*)(wr + (h >> 1));
        fma8(acc, wv, hv);
    }
    ctxg[(size_t)reord(row, 10) * 64 + lane] = acc;
}

__global__ __launch_bounds__(256) void las_ctxp1(const float* ctxT, const u16* W_p1,
                                                 const u16* b_p1, float* ctxp1) {
    int lane = threadIdx.x & 63, w = threadIdx.x >> 6;
    int i = blockIdx.x * 4 + w;
    float acc = bfc(b_p1[i]);
    const u32* wr = (const u32*)(W_p1 + (size_t)i * 1024 + 512);
    for (int h = 0; h < 512; h += 8) {
        float hv[8];
#pragma unroll
        for (int k = 0; k < 8; k++) hv[k] = ctxT[(size_t)(h + k) * 64 + lane];
        uint4 wv = *(const uint4*)(wr + (h >> 1));
        fma8(acc, wv, hv);
    }
    ctxp1[(size_t)i * 64 + lane] = acc;
}

__global__ __launch_bounds__(256) void las_b12r(const u16* bih1, const u16* bhh1,
                                                const u16* bih2, const u16* bhh2,
                                                float* b1R, float* b2R) {
    int ri = blockIdx.x * 256 + threadIdx.x;    // 4096
    int blk = ri >> 4, m = ri & 15;
    int r1 = (m & 3) * 1024 + blk * 4 + (m >> 2);
    b1R[ri] = bfc(bih1[r1]) + bfc(bhh1[r1]);
    if (ri < 2048) {
        int r2 = (m & 3) * 512 + blk * 4 + (m >> 2);
        b2R[ri] = bfc(bih2[r2]) + bfc(bhh2[r2]);
    }
}

// ---- A-fragment reorder kernels (dst element (lane&15 -> tile row m, (lane>>4)*8+j -> k)) ----

__global__ __launch_bounds__(256) void las_aL0(const void* W, const int* flag, u16* dst) {
    int idx = blockIdx.x * 256 + threadIdx.x;   // 256*32*64
    int lane = idx & 63, s = (idx >> 6) & 31, blk = idx >> 11;
    int m = lane & 15, qd = lane >> 4;
    int row = (m & 3) * 1024 + blk * 4 + (m >> 2);
    *(uint4*)(dst + (size_t)idx * 8) = ld8(W, (size_t)row * 1024 + s * 32 + qd * 8, flag[0]);
}

__global__ __launch_bounds__(256) void las_aL1(const void* Wih, const void* Whh, const int* flag, u16* dst) {
    int idx = blockIdx.x * 256 + threadIdx.x;   // 256*64*64
    int lane = idx & 63, s = (idx >> 6) & 63, blk = idx >> 12;
    int m = lane & 15, qd = lane >> 4;
    int row = (m & 3) * 1024 + blk * 4 + (m >> 2);
    uint4 v;
    if (s < 32) v = ld8(Wih, (size_t)row * 1024 + s * 32 + qd * 8, flag[0]);
    else        v = ld8(Whh, (size_t)row * 1024 + (s - 32) * 32 + qd * 8, flag[0]);
    *(uint4*)(dst + (size_t)idx * 8) = v;
}

__global__ __launch_bounds__(256) void las_aL2(const void* Wih, const void* Whh, const int* flag, u16* dst) {
    int idx = blockIdx.x * 256 + threadIdx.x;   // 128*48*64
    int lane = idx & 63, t2 = idx >> 6;
    int s = t2 % 48, blk = t2 / 48;
    int m = lane & 15, qd = lane >> 4;
    int row = (m & 3) * 512 + blk * 4 + (m >> 2);
    uint4 v;
    if (s < 32) v = ld8(Wih, (size_t)row * 1024 + s * 32 + qd * 8, flag[0]);
    else        v = ld8(Whh, (size_t)row * 512 + (s - 32) * 32 + qd * 8, flag[0]);
    *(uint4*)(dst + (size_t)idx * 8) = v;
}

__global__ __launch_bounds__(256) void las_aP1(const u16* W_p1, u16* dst) {
    int idx = blockIdx.x * 256 + threadIdx.x;   // 32*16*64
    int lane = idx & 63, s = (idx >> 6) & 15, blk = idx >> 10;
    int m = lane & 15, qd = lane >> 4;
    int row = blk * 16 + m;
    *(uint4*)(dst + (size_t)idx * 8) = *(const uint4*)(W_p1 + (size_t)row * 1024 + s * 32 + qd * 8);
}

__global__ __launch_bounds__(256) void las_aP2(const u16* W_emb, u16* dst) {
    int idx = blockIdx.x * 256 + threadIdx.x;   // 3*16*64
    if (idx >= 3 * 16 * 64) return;
    int lane = idx & 63, s = (idx >> 6) & 15, tile = idx >> 10;
    int m = lane & 15, qd = lane >> 4;
    int row = tile * 16 + m;
    uint4 v = make_uint4(0, 0, 0, 0);
    if (row < 34) v = *(const uint4*)(W_emb + (size_t)row * 512 + s * 32 + qd * 8);
    *(uint4*)(dst + (size_t)idx * 8) = v;
}

// ---------------- persistent decode kernel ----------------

__device__ __forceinline__ void gridbar(int* cnt, int* gen) {
    __syncthreads();
    if (threadIdx.x == 0) {
        __threadfence();
        int g = __hip_atomic_load(gen, __ATOMIC_RELAXED, __HIP_MEMORY_SCOPE_AGENT);
        int arrived = __hip_atomic_fetch_add(cnt, 1, __ATOMIC_ACQ_REL, __HIP_MEMORY_SCOPE_AGENT);
        if (arrived == NBLK - 1) {
            __hip_atomic_store(cnt, 0, __ATOMIC_RELAXED, __HIP_MEMORY_SCOPE_AGENT);
            __hip_atomic_store(gen, g + 1, __ATOMIC_RELEASE, __HIP_MEMORY_SCOPE_AGENT);
        } else {
            for (long it = 0; it < (1L << 20); ++it) {
                if (__hip_atomic_load(gen, __ATOMIC_ACQUIRE, __HIP_MEMORY_SCOPE_AGENT) != g) break;
                __builtin_amdgcn_s_sleep(1);
            }
        }
        __threadfence();
    }
    __syncthreads();
}

// acc += A_tile @ B, B read from hrow (= hbuf + batch*Krow [+kofs]), nslice K/32 slices
__device__ __forceinline__ v4f mmrun(const uint4* __restrict__ Afr, int nslice,
                                     const u16* __restrict__ hrow, int lane, v4f acc) {
    const uint4* bp = (const uint4*)(hrow + ((lane >> 4) << 3));
#pragma unroll 8
    for (int s = 0; s < nslice; s++) {
        U4 a, b;
        a.u = Afr[s * 64 + lane];
        b.u = bp[s * 4];
        acc = __builtin_amdgcn_mfma_f32_16x16x32_bf16(a.s, b.s, acc, 0, 0, 0);
    }
    return acc;
}

__global__ __launch_bounds__(256, 1) void las_run(
    const u16* __restrict__ aL0, const u16* __restrict__ aL1, const u16* __restrict__ aL2,
    const u16* __restrict__ aP1, const u16* __restrict__ aP2,
    u16* h0b, u16* h1b, u16* h2b, u16* yT,
    const float* __restrict__ embgR, const float* __restrict__ ctxgR,
    const float* __restrict__ ctxp1, const float* __restrict__ b1R, const float* __restrict__ b2R,
    const int* __restrict__ labT,
    const u16* __restrict__ c00c, const u16* __restrict__ c01c, const u16* __restrict__ c02c,
    const u16* __restrict__ bp2c,
    int* bars, const int* flag, void* outp) {

    __shared__ float sm[48 * 64];
    __shared__ float lse[64];

    int blk = blockIdx.x, tid = threadIdx.x;
    int w = tid >> 6, lane = tid & 63;
    int q = lane >> 4, n = lane & 15;
    int batch = w * 16 + n;
    int isb = flag[0];

    const uint4* A0 = (const uint4*)aL0 + (size_t)blk * 2048;
    const uint4* A1 = (const uint4*)aL1 + (size_t)blk * 4096;
    const uint4* A2 = (const uint4*)aL2 + (size_t)(blk < 128 ? blk : 0) * 3072;
    const uint4* AP1 = (const uint4*)aP1 + (size_t)(blk >= 224 ? blk - 224 : 0) * 1024;
    const uint4* AP2 = (const uint4*)aP2;

    float c0 = bfc(c00c[blk * 4 + q]);
    float c1 = bfc(c01c[blk * 4 + q]);
    float c2 = (blk < 128) ? bfc(c02c[blk * 4 + q]) : 0.0f;

    int riL = blk * 16 + q * 4;

    // ---- L0(0) ----
    {
        v4f acc = {0.f, 0.f, 0.f, 0.f};
        acc = mmrun(A0, 32, h0b + 65536 + batch * 1024, lane, acc);   // reads h0(-1) in buf1
        int lab = labT[batch];                                        // t = 0
        float g[4];
#pragma unroll
        for (int r = 0; r < 4; r++)
            g[r] = acc[r] + embgR[(riL + r) * 34 + lab] + ctxgR[(riL + r) * 64 + batch];
        float ig = sigf(g[0]), fg = sigf(g[1]), gg = tanh_(g[2]), og = sigf(g[3]);
        c0 = fmaf(fg, c0, ig * gg);
        h0b[batch * 1024 + blk * 4 + q] = f2bf(og * tanh_(c0));       // h0(0) -> buf0
    }
    gridbar(bars, bars + 1);

    for (int i = 0; i <= 256; i++) {
        int par = i & 1, opp = par ^ 1;
        // ======== phase B: L1(i), P2(i-2) ========
        if (i < 255) {
            v4f acc = {0.f, 0.f, 0.f, 0.f}, acc2 = {0.f, 0.f, 0.f, 0.f};
            acc  = mmrun(A1,           32, h0b + par * 65536 + batch * 1024, lane, acc);  // h0(i)
            acc2 = mmrun(A1 + 2048,    32, h1b + opp * 65536 + batch * 1024, lane, acc2); // h1(i-1)
            float g[4];
#pragma unroll
            for (int r = 0; r < 4; r++) g[r] = acc[r] + acc2[r] + b1R[riL + r];
            float ig = sigf(g[0]), fg = sigf(g[1]), gg = tanh_(g[2]), og = sigf(g[3]);
            c1 = fmaf(fg, c1, ig * gg);
            h1b[par * 65536 + batch * 1024 + blk * 4 + q] = f2bf(og * tanh_(c1));
        }
        if (blk == 255 && i >= 2) {
            int t = i - 2;
#pragma unroll
            for (int tile = 0; tile < 3; tile++) {
                v4f acc = {0.f, 0.f, 0.f, 0.f};
                acc = mmrun(AP2 + tile * 1024, 16, yT + batch * 512, lane, acc);
#pragma unroll
                for (int r = 0; r < 4; r++) {
                    int v = tile * 16 + q * 4 + r;
                    sm[v * 64 + batch] = acc[r] + ((v < 34) ? bfc(bp2c[v]) : 0.0f);
                }
            }
            __syncthreads();
            if (tid < 64) {
                float mx = -1e30f;
                for (int v = 0; v < 34; v++) mx = fmaxf(mx, sm[v * 64 + tid]);
                float se = 0.0f;
                for (int v = 0; v < 34; v++) se += __expf(sm[v * 64 + tid] - mx);
                lse[tid] = mx + __logf(se);
            }
            __syncthreads();
            for (int idx = tid; idx < 34 * 64; idx += 256) {
                int v = idx >> 6, b = idx & 63;
                float r = sm[v * 64 + b] - lse[b];
                size_t o = ((size_t)b * 255 + t) * 34 + v;
                if (isb) ((u16*)outp)[o] = f2bf(r);
                else     ((float*)outp)[o] = r;
            }
        }
        gridbar(bars, bars + 1);
        // ======== phase M: L2(i), L0(i+1), P1(i-1) ========
        if (i < 255 && blk < 128) {
            v4f acc = {0.f, 0.f, 0.f, 0.f}, acc2 = {0.f, 0.f, 0.f, 0.f};
            acc  = mmrun(A2,        32, h1b + par * 65536 + batch * 1024, lane, acc);  // h1(i)
            acc2 = mmrun(A2 + 2048, 16, h2b + opp * 32768 + batch * 512,  lane, acc2); // h2(i-1)
            float g[4];
#pragma unroll
            for (int r = 0; r < 4; r++) g[r] = acc[r] + acc2[r] + b2R[riL + r];
            float ig = sigf(g[0]), fg = sigf(g[1]), gg = tanh_(g[2]), og = sigf(g[3]);
            c2 = fmaf(fg, c2, ig * gg);
            h2b[par * 32768 + batch * 512 + blk * 4 + q] = f2bf(og * tanh_(c2));
        }
        if (i <= 253) {
            int t = i + 1;
            v4f acc = {0.f, 0.f, 0.f, 0.f};
            acc = mmrun(A0, 32, h0b + par * 65536 + batch * 1024, lane, acc);          // h0(i)=h0(t-1)
            int lab = labT[t * 64 + batch];
            float g[4];
#pragma unroll
            for (int r = 0; r < 4; r++)
                g[r] = acc[r] + embgR[(riL + r) * 34 + lab] + ctxgR[(riL + r) * 64 + batch];
            float ig = sigf(g[0]), fg = sigf(g[1]), gg = tanh_(g[2]), og = sigf(g[3]);
            c0 = fmaf(fg, c0, ig * gg);
            h0b[opp * 65536 + batch * 1024 + blk * 4 + q] = f2bf(og * tanh_(c0));      // h0(t)->buf[t&1]
        }
        if (blk >= 224 && i >= 1 && i <= 255) {
            v4f acc = {0.f, 0.f, 0.f, 0.f};
            acc = mmrun(AP1, 16, h2b + opp * 32768 + batch * 512, lane, acc);          // h2(i-1)
            int pb = blk - 224;
#pragma unroll
            for (int r = 0; r < 4; r++) {
                int yrow = pb * 16 + q * 4 + r;
                float v = acc[r] + ctxp1[yrow * 64 + batch];
                v = v > 0.0f ? v : 0.01f * v;
                yT[batch * 512 + yrow] = f2bf(v);
            }
        }
        if (i < 256) gridbar(bars, bars + 1);
    }
}

// ---------------- failure instrumentation ----------------

__global__ __launch_bounds__(256) void las_nanscan(const void* outp, const int* flag, int* cnt, int n) {
    int g = blockIdx.x * 256 + threadIdx.x;
    if (g >= n) return;
    bool bad;
    if (flag[0]) { u16 v = ((const u16*)outp)[g]; bad = ((v & 0x7F80u) == 0x7F80u); }
    else { float f = ((const float*)outp)[g]; bad = !isfinite(f); }
    if (bad) atomicAdd(cnt, 1);
}

__global__ __launch_bounds__(64) void las_nansig(void* outp, const int* flag, const int* cnt) {
    if (threadIdx.x != 0) return;
    int c = cnt[0];
    if (c > 0) {
        int cc = c < 9999 ? c : 9999;
        float sig = 10000.0f * (float)(1 + flag[0]) + (float)cc;
        if (flag[0]) ((u16*)outp)[0] = f2bf(sig);
        else         ((float*)outp)[0] = sig;
    }
}

// ---------------- host ----------------

extern "C" void kernel_launch(void* const* d_in, const int* in_sizes, int n_in,
                              void* d_out, int out_size, void* d_ws, size_t ws_size,
                              hipStream_t stream) {
    const void* keys     = d_in[0];
    const void* values   = d_in[1];
    const int* label     = (const int*)d_in[2];
    const int* input_len = (const int*)d_in[4];

    float* F     = (float*)d_ws;
    float* q     = F + O_QUERY;
    float* nq    = F + O_NQ;
    float* wk    = F + O_WK;
    float* kb    = F + O_KB;
    int*   flag  = (int*)(F + O_FLAG);
    int*   bars  = (int*)(F + O_BARS);
    float* av    = F + O_AV;
    float* head  = F + O_HEAD;
    float* ctxT  = F + O_CTXT;
    float* embg  = F + O_EMBG;
    float* ctxg  = F + O_CTXG;
    float* ctxp1 = F + O_CTXP1;
    float* b1R   = F + O_B1R;
    float* b2R   = F + O_B2R;
    int*   labT  = (int*)(F + O_LABT);
    u16*   h0b   = (u16*)(F + O_H0B);
    u16*   h1b   = (u16*)(F + O_H1B);
    u16*   h2b   = (u16*)(F + O_H2B);
    u16*   yT    = (u16*)(F + O_YT);
    u16*   pAL0  = (u16*)(F + O_AL0);
    u16*   pAL1  = (u16*)(F + O_AL1);
    u16*   pAL2  = (u16*)(F + O_AL2);
    u16*   pAP1  = (u16*)(F + O_AP1);
    u16*   pAP2  = (u16*)(F + O_AP2);
    u16*   cw    = (u16*)d_ws + 2 * (size_t)O_CANON;

    // canonicalization: d_in[6..37]; big recurrent weights (idx 15,20,21,26,27) read raw instead
    static const unsigned kLen[NSEG] = {
        17408, 34, 262144, 512, 262144, 512, 262144, 512, 262144, 512,
        262144, 512, 524288, 512, 4194304, 0, 4096, 4096, 1024, 1024,
        0, 0, 4096, 4096, 1024, 1024, 0, 0, 2048, 2048,
        512, 512
    };
    Cvt cv;
    const u16* cwp[NSEG];
    unsigned o = 0;
    for (int i = 0; i < NSEG; i++) {
        cv.src[i] = d_in[6 + i];
        cv.ofs[i] = o;
        cv.len[i] = kLen[i];
        cwp[i] = cw + o;
        o += (kLen[i] + 7u) & ~7u;
    }
    cv.ofs[NSEG] = o;

    const u16 *W_emb = cwp[0], *b_proj2 = cwp[1], *W_query = cwp[2], *b_query = cwp[3];
    const u16 *Wk = cwp[4], *bk = cwp[5], *Wq = cwp[6], *bq = cwp[7];
    const u16 *Wv = cwp[8], *bv = cwp[9], *W_mh = cwp[10], *b_mh = cwp[11];
    const u16 *W_p1 = cwp[12], *b_p1 = cwp[13], *Wih0 = cwp[14];
    const u16 *bih0 = cwp[16], *bhh0 = cwp[17], *h00 = cwp[18], *c00 = cwp[19];
    const u16 *bih1 = cwp[22], *bhh1 = cwp[23], *h01 = cwp[24], *c01 = cwp[25];
    const u16 *bih2 = cwp[28], *bhh2 = cwp[29], *h02 = cwp[30], *c02 = cwp[31];

    // dtype detect + canonicalize
    las_detect<<<1, 256, 0, stream>>>((const u16*)d_in[8], flag);
    las_convert<<<2048, 256, 0, stream>>>(cv, flag, cw);

    // one-time setup
    las_initA<<<256, 256, 0, stream>>>(h00, h01, h02, label,
                                       h0b + 65536, h1b + 65536, h2b + 32768, labT, bars);
    las_query<<<2, 256, 0, stream>>>(h02, W_query, b_query, q);
    las_nq<<<2, 256, 0, stream>>>(q, Wq, bq, nq);
    las_wk<<<8, 256, 0, stream>>>(nq, Wk, bk, wk, kb);
    las_attn<<<64, 256, 0, stream>>>(keys, values, input_len, flag, wk, kb, av);
    las_head<<<128, 256, 0, stream>>>(av, Wv, bv, head);
    las_ctx<<<128, 256, 0, stream>>>(head, W_mh, b_mh, ctxT);
    las_embg<<<545, 256, 0, stream>>>(W_emb, Wih0, embg);
    las_ctxg<<<1024, 256, 0, stream>>>(ctxT, Wih0, bih0, bhh0, ctxg);
    las_ctxp1<<<128, 256, 0, stream>>>(ctxT, W_p1, b_p1, ctxp1);
    las_b12r<<<16, 256, 0, stream>>>(bih1, bhh1, bih2, bhh2, b1R, b2R);

    // A-fragment reorders (big weights straight from d_in, dual-dtype)
    las_aL0<<<2048, 256, 0, stream>>>(d_in[21], flag, pAL0);                 // Whh0
    las_aL1<<<4096, 256, 0, stream>>>(d_in[26], d_in[27], flag, pAL1);       // Wih1, Whh1
    las_aL2<<<1536, 256, 0, stream>>>(d_in[32], d_in[33], flag, pAL2);       // Wih2, Whh2
    las_aP1<<<128, 256, 0, stream>>>(W_p1, pAP1);
    las_aP2<<<12, 256, 0, stream>>>(W_emb, pAP2);

    // persistent decode (255 steps, 2 grid barriers/step steady-state)
    las_run<<<NBLK, 256, 0, stream>>>(pAL0, pAL1, pAL2, pAP1, pAP2,
                                      h0b, h1b, h2b, yT,
                                      embg, ctxg, ctxp1, b1R, b2R, labT,
                                      c00, c01, c02, b_proj2,
                                      bars, flag, d_out);

    // diagnostics
    int n_out = 64 * 255 * 34;
    las_nanscan<<<(n_out + 255) / 256, 256, 0, stream>>>(d_out, flag, flag + 1, n_out);
    las_nansig<<<1, 64, 0, stream>>>(d_out, flag, flag + 1);
}